// Round 10
// baseline (119.790 us; speedup 1.0000x reference)
//
#include <hip/hip_runtime.h>

// Diagonal RNN scan: h_t = a_p * h_{t-1} + x_t,  a_p = 1 - relu(w_p), h_{-1}=0.
// x (B=32, L=8192, P=128) fp32, w (P,) fp32, out (B,L,P) fp32.
// R10: single-pass, depth-1 decoupled lookback, XCD-local.
//  - 512 blocks = 32 rows x 16 segs (512 steps). bid = seg*32+row => all segs
//    of a row map to XCD row%8 (round-robin heuristic; correctness-independent).
//  - Phase1: stream-scan segment (cacheable), publish aggregate + flag.
//  - Phase2: ONE poller waits on <=15 same-XCD flags (depth-1: aggregates are
//    produced concurrently by phase1, no ripple), 128 thr batched lookback.
//  - Phase3: re-read x (nt, L3-hot), seeded emit (nt stores).

typedef float f4 __attribute__((ext_vector_type(4)));

#define BB 32
#define LL 8192
#define PP 128
#define TPB 512
#define GROUPS 16                // 512 / 32 lanes
#define CHUNK 32                 // steps per group
#define BSTEPS (GROUPS * CHUNK)  // 512 steps per block
#define SPR (LL / BSTEPS)        // 16 segments per row
#define GRID (BB * SPR)          // 512 blocks (trivially co-resident)

__global__ __launch_bounds__(TPB) void k_scan(
    const float* __restrict__ x, const float* __restrict__ w,
    float* __restrict__ agg /* [BB][SPR][PP] */,
    int* __restrict__ flags /* [BB*SPR*16] (64B-padded) */,
    float* __restrict__ out) {
  const int tid = threadIdx.x;
  const int g = tid >> 5;
  const int l = tid & 31;
  const int row = blockIdx.x & 31;   // b
  const int seg = blockIdx.x >> 5;   // j : XCD = blockIdx%8 = row%8

  const f4 w4 = reinterpret_cast<const f4*>(w)[l];
  f4 a4;
  a4.x = 1.0f - fmaxf(w4.x, 0.0f);
  a4.y = 1.0f - fmaxf(w4.y, 0.0f);
  a4.z = 1.0f - fmaxf(w4.z, 0.0f);
  a4.w = 1.0f - fmaxf(w4.w, 0.0f);

  const size_t off =
      ((size_t)row * LL + (size_t)seg * BSTEPS + (size_t)g * CHUNK) * (PP / 4) + l;
  const f4* xv = reinterpret_cast<const f4*>(x) + off;

  __shared__ float sf[GROUPS][PP];
  __shared__ float sseed[GROUPS][PP];

  // ---- Phase 1: stream-scan this group's 32 steps (fills L3 with x).
  {
    f4 h = (f4)(0.0f);
#pragma unroll 8
    for (int t = 0; t < CHUNK; ++t) {
      const f4 v = xv[(size_t)t * (PP / 4)];
      h.x = fmaf(a4.x, h.x, v.x);
      h.y = fmaf(a4.y, h.y, v.y);
      h.z = fmaf(a4.z, h.z, v.z);
      h.w = fmaf(a4.w, h.w, v.w);
    }
    reinterpret_cast<f4*>(&sf[g][0])[l] = h;
  }
  __syncthreads();

  // ---- Phase 2a: publish block aggregate + flag.
  if (tid < PP) {
    const int p = tid;
    const float a = 1.0f - fmaxf(w[p], 0.0f);
    float a32 = a;
#pragma unroll
    for (int i = 0; i < 5; ++i) a32 *= a32;  // a^32
    float bf = 0.f;
#pragma unroll
    for (int g2 = 0; g2 < GROUPS; ++g2) bf = fmaf(a32, bf, sf[g2][p]);
    __hip_atomic_store(&agg[((size_t)row * SPR + seg) * PP + p], bf,
                       __ATOMIC_RELAXED, __HIP_MEMORY_SCOPE_AGENT);
  }
  __syncthreads();
  if (tid == 0 && seg < SPR - 1) {
    __hip_atomic_store(&flags[(row * SPR + seg) * 16], 1, __ATOMIC_RELEASE,
                       __HIP_MEMORY_SCOPE_AGENT);
  }

  // ---- Phase 2b: one poller waits for predecessors (same-XCD L2 lines).
  if (tid == 0) {
    for (int j = 0; j < seg; ++j) {
      while (__hip_atomic_load(&flags[(row * SPR + j) * 16], __ATOMIC_ACQUIRE,
                               __HIP_MEMORY_SCOPE_AGENT) == 0)
        __builtin_amdgcn_s_sleep(1);
    }
  }
  __syncthreads();

  // ---- Phase 2c: batched lookback + per-group seeds.
  if (tid < PP) {
    const int p = tid;
    const float a = 1.0f - fmaxf(w[p], 0.0f);
    float a32 = a;
#pragma unroll
    for (int i = 0; i < 5; ++i) a32 *= a32;  // a^32
    float aB = a32;
#pragma unroll
    for (int i = 0; i < 4; ++i) aB *= aB;    // a^512

    float hh = 0.f;
    const float* bp = agg + (size_t)row * SPR * PP + p;
    int j = 0;
    for (; j + 4 <= seg; j += 4) {
      const float v0 = bp[(size_t)(j + 0) * PP];
      const float v1 = bp[(size_t)(j + 1) * PP];
      const float v2 = bp[(size_t)(j + 2) * PP];
      const float v3 = bp[(size_t)(j + 3) * PP];
      hh = fmaf(aB, hh, v0);
      hh = fmaf(aB, hh, v1);
      hh = fmaf(aB, hh, v2);
      hh = fmaf(aB, hh, v3);
    }
    for (; j < seg; ++j) hh = fmaf(aB, hh, bp[(size_t)j * PP]);

#pragma unroll
    for (int g2 = 0; g2 < GROUPS; ++g2) {
      sseed[g2][p] = hh;
      hh = fmaf(a32, hh, sf[g2][p]);
    }
  }
  __syncthreads();

  // ---- Phase 3: seeded re-scan (x from L3, nt), nt emit.
  f4 h = reinterpret_cast<const f4*>(&sseed[g][0])[l];
  f4* ov = reinterpret_cast<f4*>(out) + off;
#pragma unroll 8
  for (int t = 0; t < CHUNK; ++t) {
    const f4 v = __builtin_nontemporal_load(&xv[(size_t)t * (PP / 4)]);
    h.x = fmaf(a4.x, h.x, v.x);
    h.y = fmaf(a4.y, h.y, v.y);
    h.z = fmaf(a4.z, h.z, v.z);
    h.w = fmaf(a4.w, h.w, v.w);
    __builtin_nontemporal_store(h, &ov[(size_t)t * (PP / 4)]);
  }
}

extern "C" void kernel_launch(void* const* d_in, const int* in_sizes, int n_in,
                              void* d_out, int out_size, void* d_ws, size_t ws_size,
                              hipStream_t stream) {
  const float* x = (const float*)d_in[0];
  const float* w = (const float*)d_in[1];
  float* out = (float*)d_out;
  int* flags = (int*)d_ws;                        // 32 KiB (64B-padded flags)
  float* agg = (float*)((char*)d_ws + 65536);     // 256 KiB

  hipMemsetAsync(flags, 0, GRID * 16 * sizeof(int), stream);
  k_scan<<<GRID, TPB, 0, stream>>>(x, w, agg, flags, out);
}

// Round 11
// 67.995 us; speedup vs baseline: 1.7618x; 1.7618x over previous
//
#include <hip/hip_runtime.h>

// Diagonal RNN scan: h_t = a_p * h_{t-1} + x_t,  a_p = 1 - relu(w_p), h_{-1}=0.
// x (B=32, L=8192, P=128) fp32, w (P,) fp32, out (B,L,P) fp32.
// R11 = champion R5 micro-tuned (sync-free 2-kernel; all sync variants lose):
//  k1: stream x (cacheable -> L3), publish per-block aggregate (1 MB).
//  k2: nt-load block slice to registers; lookback over agg HOISTED before the
//      local-final chain (overlaps with xr loads in flight); seeds; nt emit.

typedef float f4 __attribute__((ext_vector_type(4)));

#define BB 32
#define LL 8192
#define PP 128
#define TPB 256
#define CHUNK 16                 // timesteps per 32-lane group
#define GPB 8                    // groups per block
#define BSTEPS (CHUNK * GPB)     // 128 timesteps per block
#define BPR (LL / BSTEPS)        // 64 blocks per batch-row
#define GRID (BB * BPR)          // 2048 blocks

__device__ __forceinline__ f4 make_a4(const float* __restrict__ w, int l) {
  const f4 w4 = reinterpret_cast<const f4*>(w)[l];
  f4 a4;
  a4.x = 1.0f - fmaxf(w4.x, 0.0f);
  a4.y = 1.0f - fmaxf(w4.y, 0.0f);
  a4.z = 1.0f - fmaxf(w4.z, 0.0f);
  a4.w = 1.0f - fmaxf(w4.w, 0.0f);
  return a4;
}

// ---- k1: stream x, publish block aggregates --------------------------------
__global__ __launch_bounds__(TPB) void k1_aggs(
    const float* __restrict__ x, const float* __restrict__ w,
    float* __restrict__ agg /* [B][BPR][P] */) {
  const int tid = threadIdx.x;
  const int g = tid >> 5;
  const int l = tid & 31;
  const int b = blockIdx.x / BPR;
  const int s = blockIdx.x % BPR;

  const f4 a4 = make_a4(w, l);

  const f4* xv = reinterpret_cast<const f4*>(x) +
                 ((size_t)b * LL + (size_t)s * BSTEPS + (size_t)g * CHUNK) * (PP / 4) + l;
  f4 h = (f4)(0.0f);
#pragma unroll
  for (int t = 0; t < CHUNK; ++t) {
    const f4 v = xv[(size_t)t * (PP / 4)];  // cacheable: fill L3 for k2
    h.x = fmaf(a4.x, h.x, v.x);
    h.y = fmaf(a4.y, h.y, v.y);
    h.z = fmaf(a4.z, h.z, v.z);
    h.w = fmaf(a4.w, h.w, v.w);
  }

  __shared__ float sf[GPB][PP];
  reinterpret_cast<f4*>(&sf[g][0])[l] = h;
  __syncthreads();

  if (tid < PP) {
    const int p = tid;
    const float a = 1.0f - fmaxf(w[p], 0.0f);
    float a16 = a;
#pragma unroll
    for (int i = 0; i < 4; ++i) a16 *= a16;  // a^16
    float bf = 0.f;
#pragma unroll
    for (int g2 = 0; g2 < GPB; ++g2) bf = fmaf(a16, bf, sf[g2][p]);
    agg[((size_t)b * BPR + s) * PP + p] = bf;
  }
}

// ---- k2: reg-resident slice + hoisted lookback + seeded nt emit ------------
__global__ __launch_bounds__(TPB) void k2_emit(
    const float* __restrict__ x, const float* __restrict__ w,
    const float* __restrict__ agg /* [B][BPR][P] */,
    float* __restrict__ out) {
  const int tid = threadIdx.x;
  const int g = tid >> 5;
  const int l = tid & 31;
  const int b = blockIdx.x / BPR;
  const int s = blockIdx.x % BPR;

  const f4 a4 = make_a4(w, l);

  const size_t off = ((size_t)b * LL + (size_t)s * BSTEPS + (size_t)g * CHUNK) * (PP / 4) + l;
  const f4* xv = reinterpret_cast<const f4*>(x) + off;

  // Issue the 16 slice loads first (nt: last use of x; L3-hot from k1).
  f4 xr[CHUNK];
#pragma unroll
  for (int t = 0; t < CHUNK; ++t)
    xr[t] = __builtin_nontemporal_load(&xv[(size_t)t * (PP / 4)]);

  // Lookback over predecessor aggregates — depends only on agg, so it
  // overlaps with the xr loads still in flight.
  float hh = 0.f;
  float a16_s = 0.f;
  if (tid < PP) {
    const int p = tid;
    const float a = 1.0f - fmaxf(w[p], 0.0f);
    float a16 = a;
#pragma unroll
    for (int i = 0; i < 4; ++i) a16 *= a16;  // a^16
    a16_s = a16;
    float a128 = a16;
#pragma unroll
    for (int i = 0; i < 3; ++i) a128 *= a128;  // a^128

    const float* bp = agg + (size_t)b * BPR * PP + p;
    int j = 0;
    for (; j + 8 <= s; j += 8) {
      const float v0 = bp[(size_t)(j + 0) * PP];
      const float v1 = bp[(size_t)(j + 1) * PP];
      const float v2 = bp[(size_t)(j + 2) * PP];
      const float v3 = bp[(size_t)(j + 3) * PP];
      const float v4 = bp[(size_t)(j + 4) * PP];
      const float v5 = bp[(size_t)(j + 5) * PP];
      const float v6 = bp[(size_t)(j + 6) * PP];
      const float v7 = bp[(size_t)(j + 7) * PP];
      hh = fmaf(a128, hh, v0);
      hh = fmaf(a128, hh, v1);
      hh = fmaf(a128, hh, v2);
      hh = fmaf(a128, hh, v3);
      hh = fmaf(a128, hh, v4);
      hh = fmaf(a128, hh, v5);
      hh = fmaf(a128, hh, v6);
      hh = fmaf(a128, hh, v7);
    }
    for (; j < s; ++j) hh = fmaf(a128, hh, bp[(size_t)j * PP]);
  }

  // Group-local finals from registers.
  __shared__ float sf[GPB][PP];
  __shared__ float seed[GPB][PP];
  {
    f4 h = (f4)(0.0f);
#pragma unroll
    for (int t = 0; t < CHUNK; ++t) {
      h.x = fmaf(a4.x, h.x, xr[t].x);
      h.y = fmaf(a4.y, h.y, xr[t].y);
      h.z = fmaf(a4.z, h.z, xr[t].z);
      h.w = fmaf(a4.w, h.w, xr[t].w);
    }
    reinterpret_cast<f4*>(&sf[g][0])[l] = h;
  }
  __syncthreads();

  // Per-group exclusive seeds.
  if (tid < PP) {
    const int p = tid;
#pragma unroll
    for (int g2 = 0; g2 < GPB; ++g2) {
      seed[g2][p] = hh;
      hh = fmaf(a16_s, hh, sf[g2][p]);
    }
  }
  __syncthreads();

  // Seeded emit from registers.
  f4 h = reinterpret_cast<const f4*>(&seed[g][0])[l];
  f4* ov = reinterpret_cast<f4*>(out) + off;
#pragma unroll
  for (int t = 0; t < CHUNK; ++t) {
    h.x = fmaf(a4.x, h.x, xr[t].x);
    h.y = fmaf(a4.y, h.y, xr[t].y);
    h.z = fmaf(a4.z, h.z, xr[t].z);
    h.w = fmaf(a4.w, h.w, xr[t].w);
    __builtin_nontemporal_store(h, &ov[(size_t)t * (PP / 4)]);
  }
}

extern "C" void kernel_launch(void* const* d_in, const int* in_sizes, int n_in,
                              void* d_out, int out_size, void* d_ws, size_t ws_size,
                              hipStream_t stream) {
  const float* x = (const float*)d_in[0];
  const float* w = (const float*)d_in[1];
  float* out = (float*)d_out;
  float* agg = (float*)d_ws;  // 1 MiB

  k1_aggs<<<GRID, TPB, 0, stream>>>(x, w, agg);
  k2_emit<<<GRID, TPB, 0, stream>>>(x, w, agg, out);
}